// Round 8
// baseline (141.997 us; speedup 1.0000x reference)
//
#include <hip/hip_runtime.h>
#include <math.h>

#define BATCH  512
#define NROWS  256
#define NVECS  8
#define VSIZE  128
#define DIM    1024   // NVECS*VSIZE
#define NCOMBO 256

// ---------------------------------------------------------------------------
// R8 = R7 (DPP reductions, -4.3us verified) + three work-removals:
//  1. Conflict-free LDS reads: segment layout permuted (c*4+j) -> (j*8+c).
//     Old read bank (n+4c+j)%8 was 4-way conflicted within every 8-lane
//     group (R0's "conflict-free" comment was wrong); new bank (n+c)%8 is
//     distinct. Staging writes become 4-way (8 writes vs 32 reads -> net win).
//  2. w sub-norms hoisted out of the r-loop (R4-verified math), computed
//     once from LDS between two barriers: r-loop loses 16 FMA + 1 DPP-sum
//     + the sqrt/rcp chain per iteration.
//  3. v_rsq_f32 for inverse norms: rsq(max(ss,1e-16)) == 1/max(sqrt(ss),1e-8).
// ---------------------------------------------------------------------------

// sum over each 8-lane group, result in all 8 lanes (pure VALU, R7-verified)
__device__ __forceinline__ float dpp8_sum(float x) {
  int v;
  v = __builtin_amdgcn_update_dpp(0, __float_as_int(x), 0xB1, 0xF, 0xF, true);
  x += __int_as_float(v);                       // + lane^1  (quad_perm 1,0,3,2)
  v = __builtin_amdgcn_update_dpp(0, __float_as_int(x), 0x4E, 0xF, 0xF, true);
  x += __int_as_float(v);                       // + lane^2  (quad_perm 2,3,0,1)
  v = __builtin_amdgcn_update_dpp(0, __float_as_int(x), 0x141, 0xF, 0xF, true);
  x += __int_as_float(v);                       // + other quad (row_half_mirror)
  return x;
}

__global__ __launch_bounds__(256) void fused_kernel(
    const float* __restrict__ q, const float* __restrict__ w,
    float* __restrict__ out) {
  // 33 KB. Layout (float4 units): row*264 + seg*33 + (j*8 + c); 1-f4 pad/seg.
  __shared__ __align__(16) float Ws[8 * 1056];
  __shared__ float iwS[64];                     // [row][n] inverse sub-norms
  const int t    = threadIdx.x;
  const int wv   = t >> 6, lane = t & 63;
  const int bs   = blockIdx.x * 8, rs = blockIdx.y * 8;
  const int n    = lane >> 3, c = lane & 7;
  const int koff = n * VSIZE + c * 16;
  const int b0   = bs + 2 * wv;

  // stage W tile: coalesced global reads; swizzled LDS writes (j*8+c order)
  #pragma unroll
  for (int i = 0; i < 8; ++i) {
    int f   = i * 256 + t;        // float4 index 0..2047
    int row = f >> 8;             // == i (t < 256)
    int G   = f & 255;            // within-row float4 index
    int seg = G >> 5, rem = G & 31;
    int cc  = rem >> 2, jj = rem & 3;
    float4 v = *(const float4*)(w + (size_t)(rs + row) * DIM + G * 4);
    *(float4*)(Ws + row * 1056 + seg * 132 + (jj * 8 + cc) * 4) = v;
  }

  // Q rows -> registers; per-chunk inverse norms via DPP + v_rsq.
  float4 qa[4], qb[4];
  float qs0 = 0.f, qs1 = 0.f;
  {
    const float* Q0 = q + (size_t)b0 * DIM + koff;
    #pragma unroll
    for (int j = 0; j < 4; ++j) {
      qa[j] = *(const float4*)(Q0 + 4 * j);
      qb[j] = *(const float4*)(Q0 + DIM + 4 * j);
      qs0 = fmaf(qa[j].x, qa[j].x, qs0); qs0 = fmaf(qa[j].y, qa[j].y, qs0);
      qs0 = fmaf(qa[j].z, qa[j].z, qs0); qs0 = fmaf(qa[j].w, qa[j].w, qs0);
      qs1 = fmaf(qb[j].x, qb[j].x, qs1); qs1 = fmaf(qb[j].y, qb[j].y, qs1);
      qs1 = fmaf(qb[j].z, qb[j].z, qs1); qs1 = fmaf(qb[j].w, qb[j].w, qs1);
    }
  }
  qs0 = dpp8_sum(qs0);
  qs1 = dpp8_sum(qs1);
  const float iq0 = __builtin_amdgcn_rsqf(fmaxf(qs0, 1e-16f));
  const float iq1 = __builtin_amdgcn_rsqf(fmaxf(qs1, 1e-16f));

  __syncthreads();   // Ws ready

  // w sub-norms from LDS (conflict-free reads): wave wv -> rows 2wv, 2wv+1
  #pragma unroll
  for (int h = 0; h < 2; ++h) {
    const int row = 2 * wv + h;
    const float* Wr = Ws + row * 1056 + n * 132 + c * 4;
    float ss = 0.f;
    #pragma unroll
    for (int j = 0; j < 4; ++j) {
      float4 v = *(const float4*)(Wr + j * 32);
      ss = fmaf(v.x, v.x, ss); ss = fmaf(v.y, v.y, ss);
      ss = fmaf(v.z, v.z, ss); ss = fmaf(v.w, v.w, ss);
    }
    ss = dpp8_sum(ss);
    if (c == 0) iwS[row * 8 + n] = __builtin_amdgcn_rsqf(fmaxf(ss, 1e-16f));
  }

  __syncthreads();   // iwS ready

  const float* Wb = Ws + n * 132 + c * 4;
  float* out0 = out + ((size_t)b0 * NROWS + rs) * NCOMBO + lane * 4;

  #pragma unroll 2
  for (int r = 0; r < 8; ++r) {
    // --- dots for row rs+r (W from LDS, conflict-free b128 reads) ---
    const float* Wr = Wb + r * 1056;
    float s0 = 0.f, s1 = 0.f;
    #pragma unroll
    for (int j = 0; j < 4; ++j) {
      float4 w4 = *(const float4*)(Wr + j * 32);
      s0 = fmaf(qa[j].x, w4.x, s0); s0 = fmaf(qa[j].y, w4.y, s0);
      s0 = fmaf(qa[j].z, w4.z, s0); s0 = fmaf(qa[j].w, w4.w, s0);
      s1 = fmaf(qb[j].x, w4.x, s1); s1 = fmaf(qb[j].y, w4.y, s1);
      s1 = fmaf(qb[j].z, w4.z, s1); s1 = fmaf(qb[j].w, w4.w, s1);
    }
    s0 = dpp8_sum(s0);
    s1 = dpp8_sum(s1);
    const float iw  = iwS[r * 8 + n];   // per-group broadcast, conflict-free
    const float cs0 = fmaxf(s0 * iq0 * iw, 0.f);
    const float cs1 = fmaxf(s1 * iq1 * iw, 0.f);

    // broadcast cs[n] from lane 8n to all lanes (uniform index -> readlane)
    float v0[8], v1[8];
    #pragma unroll
    for (int j = 0; j < 8; ++j) {
      v0[j] = __shfl(cs0, j * 8, 64);
      v1[j] = __shfl(cs1, j * 8, 64);
    }

    // --- expand + store both b-rows for this r (stores spread over loop) ---
    #pragma unroll
    for (int pp = 0; pp < 2; ++pp) {
      const float* v = pp ? v1 : v0;
      float t2 = (lane & 1)  ? 1.f - v[2] : v[2];
      float t3 = (lane & 2)  ? 1.f - v[3] : v[3];
      float t4 = (lane & 4)  ? 1.f - v[4] : v[4];
      float t5 = (lane & 8)  ? 1.f - v[5] : v[5];
      float t6 = (lane & 16) ? 1.f - v[6] : v[6];
      float t7 = (lane & 32) ? 1.f - v[7] : v[7];
      float base = ((t2 * t3) * (t4 * t5)) * (t6 * t7);
      float c0 = v[0], c1 = v[1];
      float4 o;
      o.x = base * (c0 * c1);
      o.y = base * ((1.f - c0) * c1);
      o.z = base * (c0 * (1.f - c1));
      o.w = base * ((1.f - c0) * (1.f - c1));
      *(float4*)(out0 + ((size_t)pp * NROWS + r) * NCOMBO) = o;
    }
  }
}

// ---------------------------------------------------------------------------
extern "C" void kernel_launch(void* const* d_in, const int* in_sizes, int n_in,
                              void* d_out, int out_size, void* d_ws, size_t ws_size,
                              hipStream_t stream) {
  const float* query  = (const float*)d_in[0];   // [512][1024]
  const float* weight = (const float*)d_in[1];   // [256][1024]
  float* out = (float*)d_out;                    // [512][256][256]
  (void)d_ws; (void)ws_size;

  hipLaunchKernelGGL(fused_kernel, dim3(64, 32), dim3(256), 0, stream,
                     query, weight, out);
}